// Round 15
// baseline (513.247 us; speedup 1.0000x reference)
//
#include <hip/hip_runtime.h>
#include <math.h>

#define BSZ 4096        // B*S
#define HDIM 1024
#define IDIM 4096
#define QKVN 3072
#define NEGF (-1000000000.0f)

typedef __attribute__((ext_vector_type(8))) short bf16x8s;   // 8 bf16 in 4 VGPR
typedef __attribute__((ext_vector_type(4))) float f32x4;
typedef __attribute__((ext_vector_type(2))) unsigned int u32x2;
typedef __attribute__((ext_vector_type(4))) unsigned int u32x4;

#define GLDS(src, dst) __builtin_amdgcn_global_load_lds( \
    (const __attribute__((address_space(1))) void*)(src), \
    (__attribute__((address_space(3))) void*)(dst), 16, 0, 0)

__device__ inline unsigned short f2bf(float f){
  __bf16 h = (__bf16)f;
  return __builtin_bit_cast(unsigned short, h);
}
__device__ inline float bf2f(unsigned short u){
  unsigned x = ((unsigned)u) << 16;
  return __builtin_bit_cast(float, x);
}

__device__ inline float wredSum(float v){
  #pragma unroll
  for (int off = 32; off; off >>= 1) v += __shfl_xor(v, off);
  return v;
}

// ---------------- router: scores, argmax, gates, copy hidden -> out --------------
__global__ __launch_bounds__(256) void router_kernel(
    const float* __restrict__ hidden, const float* __restrict__ ek,
    float* __restrict__ out, float* __restrict__ act0, float* __restrict__ act1,
    float* __restrict__ g0, float* __restrict__ g1)
{
  const int lane = threadIdx.x & 63, wid = threadIdx.x >> 6;
  const int row = blockIdx.x * 4 + wid;
  const float* hr = hidden + (size_t)row * HDIM;
  float4 xv[4];
  float s0 = 0.f, s1 = 0.f, s2 = 0.f, s3 = 0.f;
  #pragma unroll
  for (int tt = 0; tt < 4; ++tt){
    const int o = tt * 256 + lane * 4;
    xv[tt] = *(const float4*)&hr[o];
    const float4 e0 = *(const float4*)&ek[0 * HDIM + o];
    const float4 e1 = *(const float4*)&ek[1 * HDIM + o];
    const float4 e2 = *(const float4*)&ek[2 * HDIM + o];
    const float4 e3 = *(const float4*)&ek[3 * HDIM + o];
    s0 += xv[tt].x * e0.x + xv[tt].y * e0.y + xv[tt].z * e0.z + xv[tt].w * e0.w;
    s1 += xv[tt].x * e1.x + xv[tt].y * e1.y + xv[tt].z * e1.z + xv[tt].w * e1.w;
    s2 += xv[tt].x * e2.x + xv[tt].y * e2.y + xv[tt].z * e2.z + xv[tt].w * e2.w;
    s3 += xv[tt].x * e3.x + xv[tt].y * e3.y + xv[tt].z * e3.z + xv[tt].w * e3.w;
  }
  s0 = wredSum(s0); s1 = wredSum(s1); s2 = wredSum(s2); s3 = wredSum(s3);
  int ch = 0; float mx = s0;
  if (s1 > mx){ mx = s1; ch = 1; }
  if (s2 > mx){ mx = s2; ch = 2; }
  if (s3 > mx){ mx = s3; ch = 3; }
  const float den = expf(s0 - mx) + expf(s1 - mx) + expf(s2 - mx) + expf(s3 - mx);
  const float wsel = 1.0f / den;
  if (lane == 0){
    const float a0 = (float)(ch & 1), a1 = (float)((ch >> 1) & 1);
    act0[row] = a0; act1[row] = a1; g0[row] = a0 * wsel; g1[row] = a1 * wsel;
  }
  float* orow = out + (size_t)row * HDIM;
  #pragma unroll
  for (int tt = 0; tt < 4; ++tt) *(float4*)&orow[tt * 256 + lane * 4] = xv[tt];
}

// ---------------- per-(batch,depth) stable compaction scan ------------------------
__global__ __launch_bounds__(1024) void scan_kernel(
    const float* __restrict__ act0, const float* __restrict__ act1,
    int* __restrict__ idx0, int* __restrict__ idx1,
    int* __restrict__ cnt0, int* __restrict__ cnt1)
{
  __shared__ int s[1024];
  const int b = blockIdx.x >> 1, d = blockIdx.x & 1;
  const float* act = d ? act1 : act0;
  int* idx = d ? idx1 : idx0;
  int* cnt = d ? cnt1 : cnt0;
  const int t = threadIdx.x;
  const int f = (act[b * 1024 + t] > 0.5f) ? 1 : 0;
  s[t] = f;
  __syncthreads();
  for (int off = 1; off < 1024; off <<= 1){
    const int v = (t >= off) ? s[t - off] : 0;
    __syncthreads();
    s[t] += v;
    __syncthreads();
  }
  if (f) idx[b * 1024 + (s[t] - 1)] = b * 1024 + t;
  if (t == 1023) cnt[b] = s[t];
}

// ---------------- ALL weight transposes in ONE dispatch --------------------------
__global__ __launch_bounds__(256) void wtr_all(
    const float* __restrict__ Wq, const float* __restrict__ Wk,
    const float* __restrict__ Wv, const float* __restrict__ Wo,
    const float* __restrict__ Wg, const float* __restrict__ Wu,
    const float* __restrict__ Wd, unsigned short* __restrict__ Wb)
{
  __shared__ float T[64][65];
  const int bidx = blockIdx.x;
  const int d = bidx >> 12;
  const int r = bidx & 4095;
  const float* src; unsigned short* dst; int K, N, tn, tk;
  unsigned short* wt = Wb + (size_t)d * 16777216;
  if (r < 1024){
    const int seg = r >> 8, t = r & 255;
    K = 1024; N = 1024; tn = t & 15; tk = t >> 4;
    const float* s4 = (seg == 0) ? Wq : (seg == 1) ? Wk : (seg == 2) ? Wv : Wo;
    src = s4 + (size_t)d * 1048576;
    dst = wt + (size_t)seg * 1048576;
  } else {
    const int r2 = r - 1024;
    const int seg = r2 >> 10, t = r2 & 1023;
    if (seg == 0){ src = Wg + (size_t)d * 4194304; dst = wt + 4194304;  K = 1024; N = 4096; tn = t & 63; tk = t >> 6; }
    else if (seg == 1){ src = Wu + (size_t)d * 4194304; dst = wt + 8388608;  K = 1024; N = 4096; tn = t & 63; tk = t >> 6; }
    else { src = Wd + (size_t)d * 4194304; dst = wt + 12582912; K = 4096; N = 1024; tn = t & 15; tk = t >> 4; }
  }
  const int k0 = tk * 64, n0 = tn * 64;
  const int tid = threadIdx.x;
  const int tx = tid & 15, ty = tid >> 4;
  #pragma unroll
  for (int i = 0; i < 4; ++i){
    const float4 v = *(const float4*)&src[(size_t)(k0 + ty + i*16) * N + n0 + tx*4];
    T[ty + i*16][tx*4 + 0] = v.x;
    T[ty + i*16][tx*4 + 1] = v.y;
    T[ty + i*16][tx*4 + 2] = v.z;
    T[ty + i*16][tx*4 + 3] = v.w;
  }
  __syncthreads();
  #pragma unroll
  for (int i = 0; i < 4; ++i){
    ushort4 u;
    u.x = f2bf(T[tx*4 + 0][ty + i*16]);
    u.y = f2bf(T[tx*4 + 1][ty + i*16]);
    u.z = f2bf(T[tx*4 + 2][ty + i*16]);
    u.w = f2bf(T[tx*4 + 3][ty + i*16]);
    *(ushort4*)&dst[(size_t)(n0 + ty + i*16) * K + k0 + tx*4] = u;
  }
}

// ---------------- gather rmsnorm: compact row <- full row via idx ----------------
__global__ __launch_bounds__(256) void rms_gather(
    const float* __restrict__ src, const float* __restrict__ ekrow,
    const float* __restrict__ g,
    const int* __restrict__ idx, const int* __restrict__ cnt,
    float* __restrict__ xout, unsigned short* __restrict__ hn)
{
  const int crow = blockIdx.x;
  if ((crow & 1023) >= cnt[crow >> 10]) return;
  const int orig = idx[crow];
  const int t = threadIdx.x;
  const int lane = t & 63, wid = t >> 6;
  const float* sr = src + (size_t)orig * HDIM;
  float4 xv = *(const float4*)&sr[t * 4];
  const float4 e = *(const float4*)&ekrow[t * 4];
  xv.x += e.x; xv.y += e.y; xv.z += e.z; xv.w += e.w;
  float ss = xv.x*xv.x + xv.y*xv.y + xv.z*xv.z + xv.w*xv.w;
  ss = wredSum(ss);
  __shared__ float red[4];
  if (lane == 0) red[wid] = ss;
  __syncthreads();
  const float tot = red[0] + red[1] + red[2] + red[3];
  const float inv = rsqrtf(tot * (1.0f / HDIM) + 1e-6f);
  *(float4*)&xout[(size_t)crow * HDIM + t * 4] = xv;
  const float4 gg = *(const float4*)&g[t * 4];
  ushort4 hu;
  hu.x = f2bf(xv.x * inv * gg.x); hu.y = f2bf(xv.y * inv * gg.y);
  hu.z = f2bf(xv.z * inv * gg.z); hu.w = f2bf(xv.w * inv * gg.w);
  *(ushort4*)&hn[(size_t)crow * HDIM + t * 4] = hu;
}

// ---------------- compact rmsnorm (post-attn) ------------------------------------
__global__ __launch_bounds__(256) void rms_compact(
    const float* __restrict__ src, const float* __restrict__ g,
    const int* __restrict__ cnt, unsigned short* __restrict__ hn)
{
  const int crow = blockIdx.x;
  if ((crow & 1023) >= cnt[crow >> 10]) return;
  const int t = threadIdx.x;
  const int lane = t & 63, wid = t >> 6;
  const float* sr = src + (size_t)crow * HDIM;
  float4 xv = *(const float4*)&sr[t * 4];
  float ss = xv.x*xv.x + xv.y*xv.y + xv.z*xv.z + xv.w*xv.w;
  ss = wredSum(ss);
  __shared__ float red[4];
  if (lane == 0) red[wid] = ss;
  __syncthreads();
  const float tot = red[0] + red[1] + red[2] + red[3];
  const float inv = rsqrtf(tot * (1.0f / HDIM) + 1e-6f);
  const float4 gg = *(const float4*)&g[t * 4];
  ushort4 hu;
  hu.x = f2bf(xv.x * inv * gg.x); hu.y = f2bf(xv.y * inv * gg.y);
  hu.z = f2bf(xv.z * inv * gg.z); hu.w = f2bf(xv.w * inv * gg.w);
  *(ushort4*)&hn[(size_t)crow * HDIM + t * 4] = hu;
}

// ---------------- scatter: out[idx] += gate*(wR + p0+p1+p2+p3) (bf16 partials) ---
__global__ __launch_bounds__(256) void scatter_down4(
    const unsigned short* __restrict__ pA, const unsigned short* __restrict__ pB,
    const float* __restrict__ wR, const float* __restrict__ gate,
    const int* __restrict__ idx, const int* __restrict__ cnt,
    float* __restrict__ out)
{
  const int crow = blockIdx.x;
  if ((crow & 1023) >= cnt[crow >> 10]) return;
  const int orig = idx[crow];
  const int t = threadIdx.x;
  const float gv = gate[orig];
  const size_t off = (size_t)crow * HDIM + t * 4;
  const ushort4 a0 = *(const ushort4*)&pA[off];
  const ushort4 a1 = *(const ushort4*)&pA[4194304 + off];
  const ushort4 a2 = *(const ushort4*)&pB[off];
  const ushort4 a3 = *(const ushort4*)&pB[4194304 + off];
  const float4 rv = *(const float4*)&wR[off];
  float4 ov = *(float4*)&out[(size_t)orig * HDIM + t * 4];
  ov.x += gv * (rv.x + bf2f(a0.x) + bf2f(a1.x) + bf2f(a2.x) + bf2f(a3.x));
  ov.y += gv * (rv.y + bf2f(a0.y) + bf2f(a1.y) + bf2f(a2.y) + bf2f(a3.y));
  ov.z += gv * (rv.z + bf2f(a0.z) + bf2f(a1.z) + bf2f(a2.z) + bf2f(a3.z));
  ov.w += gv * (rv.w + bf2f(a0.w) + bf2f(a1.w) + bf2f(a2.w) + bf2f(a3.w));
  *(float4*)&out[(size_t)orig * HDIM + t * 4] = ov;
}

// swizzle helpers: LDS[row][slot16B] holds global slot (slot ^ fsw(row))
__device__ inline int fsw(int row){ return (row >> 1) & 3; }

// XCD remap for 64(M) x (NJ*16)(N) tiles, m-fast
template<int NJ>
__device__ inline void xcd_remap64(int bandM, int bandN, int& bm, int& bn){
  const int gx = gridDim.x;
  int bid = blockIdx.y * gx + blockIdx.x;
  const int xcd = bid & 7, c = bid >> 3;
  const int xcdCols = gx / bandN;
  const int xr = xcd / xcdCols, xc = xcd % xcdCols;
  const int dm = c % bandM, dn = c / bandM;
  bm = (xr * bandM + dm) * 64;
  bn = (xc * bandN + dn) * (NJ * 16);
}

// ---------------- bf16 MFMA GEMM, 64 x (NJ*16) tile, double-buffered -------------
// Wave w owns rows [w*16, w*16+16) x all NJ*16 cols: 1 A-frag, NJ B-frags.
// EPI 0: Cb = bf16(acc)  (+ optional fused RoPE on cols < 2048)
// EPI 1: Cf = res + acc                      (f32, compact)
// EPI 2: bf16 partial store by z-slice: pz[cidx] = bf16(acc)
template<int EPI, int ROPE, int NJ>
__global__ __launch_bounds__(256) void gemm64_bf16(
    const unsigned short* __restrict__ A, const unsigned short* __restrict__ Bt,
    int N, int K, int kspan,
    unsigned short* __restrict__ Cb, float* __restrict__ Cf,
    const float* __restrict__ res,
    unsigned short* __restrict__ pA, unsigned short* __restrict__ pB,
    const int* __restrict__ idx, const int* __restrict__ cnt,
    int bandM, int bandN)
{
  __shared__ __align__(16) unsigned short As[4096];        // 2 bufs x 64x32
  __shared__ __align__(16) unsigned short Bs[NJ * 1024];   // 2 bufs x (NJ*16)x32
  const int tid = threadIdx.x;
  const int lane = tid & 63, w = tid >> 6;
  const int g = lane >> 4;
  int bm, bn;
  xcd_remap64<NJ>(bandM, bandN, bm, bn);
  if ((bm & 1023) >= cnt[bm >> 10]) return;
  const int kb = blockIdx.z * kspan;
  const int BUFB = NJ * 512;                               // shorts per B buffer

  const int rr = tid >> 2, c0 = tid & 3;
  const int scc = (c0 ^ fsw(rr)) * 8;                      // fsw(rr+64) == fsw(rr)
  const unsigned short* gA  = A  + (size_t)(bm + rr) * K + kb + scc;
  const unsigned short* gB0 = Bt + (size_t)(bn + rr) * K + kb + scc;
  const unsigned short* gB1 = (NJ == 8) ? (Bt + (size_t)(bn + 64 + rr) * K + kb + scc) : nullptr;
  char* ldsA = (char*)As + w * 1024;
  char* ldsB = (char*)Bs + w * 1024;

  const int arow = w * 16 + (lane & 15);
  const int aoffw = arow * 64 + ((g ^ fsw(arow)) * 16);
  int boff[NJ];
  #pragma unroll
  for (int j = 0; j < NJ; ++j){
    const int br = j * 16 + (lane & 15);
    boff[j] = br * 64 + ((g ^ fsw(br)) * 16);
  }

  f32x4 acc[NJ];
  #pragma unroll
  for (int j = 0; j < NJ; ++j){ f32x4 z = {0.f,0.f,0.f,0.f}; acc[j] = z; }

  GLDS(gA, ldsA);
  GLDS(gB0, ldsB);
  if constexpr (NJ == 8) GLDS(gB1, ldsB + 4096);
  gA += 32; gB0 += 32;
  if constexpr (NJ == 8) gB1 += 32;
  __syncthreads();

  const int nk = kspan >> 5;
  for (int kt = 0; kt < nk; ++kt){
    const int cur = kt & 1;
    if (kt + 1 < nk){
      char* dA = ldsA + ((cur ^ 1) ? 4096 : 0);
      char* dB = ldsB + ((cur ^ 1) ? (NJ * 1024) : 0);
      GLDS(gA, dA); GLDS(gB0, dB);
      if constexpr (NJ == 8) GLDS(gB1, dB + 4096);
      gA += 32; gB0 += 32;
      if constexpr (NJ == 8) gB1 += 32;
    }
    const char* ta = (const char*)As + cur * 4096;
    const char* tb = (const char*)Bs + cur * (NJ * 1024);
    const bf16x8s af = *(const bf16x8s*)(ta + aoffw);
    #pragma unroll
    for (int j = 0; j < NJ; ++j){
      const bf16x8s bf = *(const bf16x8s*)(tb + boff[j]);
      acc[j] = __builtin_amdgcn_mfma_f32_16x16x32_bf16(af, bf, acc[j], 0, 0, 0);
    }
    __syncthreads();
  }

  const int rowb = bm + w * 16 + g * 4;

  if constexpr (ROPE){
    if (bn < 2048){
      float pos[4];
      #pragma unroll
      for (int r = 0; r < 4; ++r) pos[r] = (float)(idx[rowb + r] & 1023);
      // 8 unique angles: (jp, r); reused across heads in this tile
      float snv[2][4], csv[2][4];
      #pragma unroll
      for (int jp = 0; jp < 2; ++jp){
        const int d0 = (lane & 15) + jp * 16;            // in [0,32)
        const float invf = exp2f((float)d0 * (-13.287712379549449f / 32.0f));
        #pragma unroll
        for (int r = 0; r < 4; ++r)
          __sincosf(pos[r] * invf, &snv[jp][r], &csv[jp][r]);
      }
      #pragma unroll
      for (int hj = 0; hj < NJ / 4; ++hj){
        #pragma unroll
        for (int jp = 0; jp < 2; ++jp){
          #pragma unroll
          for (int r = 0; r < 4; ++r){
            const float sn = snv[jp][r], cs = csv[jp][r];
            const float a = acc[hj*4 + jp][r], b = acc[hj*4 + jp + 2][r];
            acc[hj*4 + jp][r]     = a * cs - b * sn;
            acc[hj*4 + jp + 2][r] = b * cs + a * sn;
          }
        }
      }
    }
  }

  unsigned short* po = nullptr;
  if constexpr (EPI == 2){
    const int z = blockIdx.z;
    po = (z < 2) ? (pA + (size_t)z * 4194304) : (pB + (size_t)(z - 2) * 4194304);
  }

  #pragma unroll
  for (int j = 0; j < NJ; ++j){
    const int gc = bn + j * 16 + (lane & 15);
    #pragma unroll
    for (int r = 0; r < 4; ++r){
      const size_t cidx = (size_t)(rowb + r) * N + gc;
      if constexpr (EPI == 0){
        Cb[cidx] = f2bf(acc[j][r]);
      } else if constexpr (EPI == 1){
        Cf[cidx] = res[cidx] + acc[j][r];
      } else {
        po[cidx] = f2bf(acc[j][r]);
      }
    }
  }
}

// ---------------- fused gate-up GEMM, 64 x (NJ*16) tile --------------------------
template<int NJ>
__global__ __launch_bounds__(256) void gemm_gu64_bf16(
    const unsigned short* __restrict__ A, const unsigned short* __restrict__ Gt,
    const unsigned short* __restrict__ Ut, int N, int K,
    unsigned short* __restrict__ P, const int* __restrict__ cnt,
    int bandM, int bandN)
{
  __shared__ __align__(16) unsigned short As[4096];
  __shared__ __align__(16) unsigned short Gs[NJ * 1024];
  __shared__ __align__(16) unsigned short Us[NJ * 1024];
  const int tid = threadIdx.x;
  const int lane = tid & 63, w = tid >> 6;
  const int g = lane >> 4;
  int bm, bn;
  xcd_remap64<NJ>(bandM, bandN, bm, bn);
  if ((bm & 1023) >= cnt[bm >> 10]) return;

  const int rr = tid >> 2, c0 = tid & 3;
  const int scc = (c0 ^ fsw(rr)) * 8;
  const unsigned short* gA  = A  + (size_t)(bm + rr) * K + scc;
  const unsigned short* gG0 = Gt + (size_t)(bn + rr) * K + scc;
  const unsigned short* gU0 = Ut + (size_t)(bn + rr) * K + scc;
  const unsigned short* gG1 = (NJ == 8) ? (Gt + (size_t)(bn + 64 + rr) * K + scc) : nullptr;
  const unsigned short* gU1 = (NJ == 8) ? (Ut + (size_t)(bn + 64 + rr) * K + scc) : nullptr;
  char* ldsA = (char*)As + w * 1024;
  char* ldsG = (char*)Gs + w * 1024;
  char* ldsU = (char*)Us + w * 1024;

  const int arow = w * 16 + (lane & 15);
  const int aoffw = arow * 64 + ((g ^ fsw(arow)) * 16);
  int boff[NJ];
  #pragma unroll
  for (int j = 0; j < NJ; ++j){
    const int br = j * 16 + (lane & 15);
    boff[j] = br * 64 + ((g ^ fsw(br)) * 16);
  }

  f32x4 accG[NJ], accU[NJ];
  #pragma unroll
  for (int j = 0; j < NJ; ++j){
    f32x4 z = {0.f,0.f,0.f,0.f}; accG[j] = z; accU[j] = z;
  }

  GLDS(gA, ldsA);
  GLDS(gG0, ldsG); GLDS(gU0, ldsU);
  if constexpr (NJ == 8){ GLDS(gG1, ldsG + 4096); GLDS(gU1, ldsU + 4096); }
  gA += 32; gG0 += 32; gU0 += 32;
  if constexpr (NJ == 8){ gG1 += 32; gU1 += 32; }
  __syncthreads();

  const int nk = K >> 5;
  for (int kt = 0; kt < nk; ++kt){
    const int cur = kt & 1;
    if (kt + 1 < nk){
      char* dA = ldsA + ((cur ^ 1) ? 4096 : 0);
      char* dG = ldsG + ((cur ^ 1) ? (NJ * 1024) : 0);
      char* dU = ldsU + ((cur ^ 1) ? (NJ * 1024) : 0);
      GLDS(gA, dA);
      GLDS(gG0, dG); GLDS(gU0, dU);
      if constexpr (NJ == 8){ GLDS(gG1, dG + 4096); GLDS(gU1, dU + 4096); }
      gA += 32; gG0 += 32; gU0 += 32;
      if constexpr (NJ == 8){ gG1 += 32; gU1 += 32; }
    }
    const char* ta = (const char*)As + cur * 4096;
    const char* tg = (const char*)Gs + cur * (NJ * 1024);
    const char* tu = (const char*)Us + cur * (NJ * 1024);
    const bf16x8s af = *(const bf16x8s*)(ta + aoffw);
    #pragma unroll
    for (int j = 0; j < NJ; ++j){
      const bf16x8s gf = *(const bf16x8s*)(tg + boff[j]);
      const bf16x8s uf = *(const bf16x8s*)(tu + boff[j]);
      accG[j] = __builtin_amdgcn_mfma_f32_16x16x32_bf16(af, gf, accG[j], 0, 0, 0);
      accU[j] = __builtin_amdgcn_mfma_f32_16x16x32_bf16(af, uf, accU[j], 0, 0, 0);
    }
    __syncthreads();
  }

  const int rowb = bm + w * 16 + g * 4;
  #pragma unroll
  for (int j = 0; j < NJ; ++j){
    const int gc = bn + j * 16 + (lane & 15);
    #pragma unroll
    for (int r = 0; r < 4; ++r){
      const float gv = accG[j][r];
      const float s = gv / (1.0f + expf(-gv));
      P[(size_t)(rowb + r) * N + gc] = f2bf(s * accU[j][r]);
    }
  }
}

// ---------------- MFMA flash attention, double-buffered K/V staging --------------
__global__ __launch_bounds__(256) void attn_mfma(
    const unsigned short* __restrict__ q, const unsigned short* __restrict__ k,
    const unsigned short* __restrict__ v,
    const int* __restrict__ idx, const int* __restrict__ cnt,
    unsigned short* __restrict__ o, int LD)
{
  __shared__ __align__(16) unsigned short K_s[2][4096];    // [64 key][64 d] swizzled
  __shared__ __align__(16) unsigned short V_t[2][64 * 72]; // [64 dd][72 key-pad]
  __shared__ int pos_s[2][64];
  const int tid = threadIdx.x;
  const int lane = tid & 63, w = tid >> 6;
  const int g = lane >> 4;
  const int b = blockIdx.z, h = blockIdx.y, qt = blockIdx.x;
  const int cntb = cnt[b];
  if (qt * 64 >= cntb) return;
  const int qw = qt * 64 + w * 16;
  const int qglob = qw + (lane & 15);                      // compact row within batch
  const int qpos = (qglob < cntb) ? (idx[b * 1024 + qglob] & 1023) : (1 << 29);
  const int lastValid = min(qt * 64 + 63, cntb - 1);
  const int maxQpos = idx[b * 1024 + lastValid] & 1023;

  bf16x8s qa[2];
  {
    const size_t qrow = (size_t)(b * 1024 + qglob) * LD + h * 64;
    qa[0] = *(const bf16x8s*)&q[qrow + g * 8];
    qa[1] = *(const bf16x8s*)&q[qrow + 32 + g * 8];
  }

  f32x4 oacc[4];
  #pragma unroll
  for (int n = 0; n < 4; ++n){ f32x4 z = {0.f,0.f,0.f,0.f}; oacc[n] = z; }
  float m_r = -3.0e38f, l_r = 0.f;

  const int key0 = (tid >> 4) * 4;
  const int dd0  = (tid & 15) * 4;

  // ---- prologue: stage chunk 0 into buf 0 ----
  {
    #pragma unroll
    for (int p = 0; p < 2; ++p){
      const int cc = tid + p * 256;
      const int key = cc >> 3, ci = cc & 7;
      const int sci = (ci ^ (key & 7)) * 8;
      const unsigned short* src = k + (size_t)(b * 1024 + key) * LD + h * 64 + sci;
      GLDS(src, (char*)K_s[0] + p * 4096 + w * 1024);
    }
    ushort4 rr[4];
    #pragma unroll
    for (int kk = 0; kk < 4; ++kk)
      rr[kk] = *(const ushort4*)&v[(size_t)(b * 1024 + key0 + kk) * LD + h * 64 + dd0];
    #pragma unroll
    for (int cdd = 0; cdd < 4; ++cdd){
      ushort4 wv;
      wv.x = ((const unsigned short*)&rr[0])[cdd];
      wv.y = ((const unsigned short*)&rr[1])[cdd];
      wv.z = ((const unsigned short*)&rr[2])[cdd];
      wv.w = ((const unsigned short*)&rr[3])[cdd];
      *(ushort4*)&V_t[0][(dd0 + cdd) * 72 + key0] = wv;
    }
    if (tid < 64)
      pos_s[0][tid] = (tid < cntb) ? (idx[b * 1024 + tid] & 1023) : (1 << 29);
  }
  __syncthreads();

  for (int c = 0; ; ++c){
    const int cur = c & 1;
    const int ck0 = c * 64;
    const int ck0n = ck0 + 64;
    const bool vn = (ck0n < cntb) && ((idx[b * 1024 + ck0n] & 1023) <= maxQpos);

    // ---- issue next chunk's loads before computing this one ----
    ushort4 rr[4];
    int myp = 0;
    if (vn){
      #pragma unroll
      for (int p = 0; p < 2; ++p){
        const int cc = tid + p * 256;
        const int key = cc >> 3, ci = cc & 7;
        const int sci = (ci ^ (key & 7)) * 8;
        const unsigned short* src = k + (size_t)(b * 1024 + ck0n + key) * LD + h * 64 + sci;
        GLDS(src, (char*)K_s[cur ^ 1] + p * 4096 + w * 1024);
      }
      #pragma unroll
      for (int kk = 0; kk < 4; ++kk)
        rr[kk] = *(const ushort4*)&v[(size_t)(b * 1024 + ck0n + key0 + kk) * LD + h * 64 + dd0];
      if (tid < 64)
        myp = (ck0n + tid < cntb) ? (idx[b * 1024 + ck0n + tid] & 1023) : (1 << 29);
    }

    // ---- compute chunk c from buf cur ----
    f32x4 s[4];
    #pragma unroll
    for (int mt = 0; mt < 4; ++mt){ f32x4 z = {0.f,0.f,0.f,0.f}; s[mt] = z; }
    #pragma unroll
    for (int kd = 0; kd < 2; ++kd){
      #pragma unroll
      for (int mt = 0; mt < 4; ++mt){
        const int row = mt * 16 + (lane & 15);
        const int slot = (kd * 4 + g) ^ (row & 7);
        const bf16x8s kf = *(const bf16x8s*)((const char*)K_s[cur] + row * 128 + slot * 16);
        s[mt] = __builtin_amdgcn_mfma_f32_16x16x32_bf16(kf, qa[kd], s[mt], 0, 0, 0);
      }
    }

    float sval[4][4];
    float rm = -3.0e38f;
    #pragma unroll
    for (int mt = 0; mt < 4; ++mt){
      const int4 pv = *(const int4*)&pos_s[cur][mt * 16 + g * 4];
      const int kp[4] = {pv.x, pv.y, pv.z, pv.w};
      #pragma unroll
      for (int r = 0; r < 4; ++r){
        float x = (kp[r] > qpos) ? -2.0e9f : s[mt][r] * 0.125f;
        sval[mt][r] = x;
        rm = fmaxf(rm, x);
      }
    }
    rm = fmaxf(rm, __shfl_xor(rm, 16));
    rm = fmaxf(rm, __shfl_xor(rm, 32));
    const float mn = fmaxf(m_r, rm);
    const float sc = expf(m_r - mn);
    float psum = 0.f;
    u32x2 pa[4];
    #pragma unroll
    for (int mt = 0; mt < 4; ++mt){
      float p0 = expf(sval[mt][0] - mn), p1 = expf(sval[mt][1] - mn);
      float p2 = expf(sval[mt][2] - mn), p3 = expf(sval[mt][3] - mn);
      psum += (p0 + p1) + (p2 + p3);
      u32x2 pw;
      pw[0] = (unsigned)f2bf(p0) | ((unsigned)f2bf(p1) << 16);
      pw[1] = (unsigned)f2bf(p2) | ((unsigned)f2bf(p3) << 16);
      pa[mt] = pw;
    }
    psum += __shfl_xor(psum, 16);
    psum += __shfl_xor(psum, 32);
    l_r = l_r * sc + psum;
    m_r = mn;

    float scq[4];
    #pragma unroll
    for (int r = 0; r < 4; ++r) scq[r] = __shfl(sc, (g << 2) | r);
    #pragma unroll
    for (int n = 0; n < 4; ++n)
      #pragma unroll
      for (int r = 0; r < 4; ++r) oacc[n][r] *= scq[r];

    #pragma unroll
    for (int half = 0; half < 2; ++half){
      unsigned aw[4];
      #pragma unroll
      for (int t = 0; t < 4; ++t){
        const int sidx = (lane & 15) + 16 * (2 * (g & 1) + (t >> 1));
        const unsigned wa = __shfl(pa[2 * half][t & 1], sidx);
        const unsigned wb = __shfl(pa[2 * half + 1][t & 1], sidx);
        aw[t] = (g < 2) ? wa : wb;
      }
      u32x4 av4 = {aw[0], aw[1], aw[2], aw[3]};
      const bf16x8s pfrag = __builtin_bit_cast(bf16x8s, av4);
      #pragma unroll
      for (int n = 0; n < 4; ++n){
        const bf16x8s vfrag = *(const bf16x8s*)&V_t[cur][(n * 16 + (lane & 15)) * 72 + half * 32 + g * 8];
        oacc[n] = __builtin_amdgcn_mfma_f32_16x16x32_bf16(pfrag, vfrag, oacc[n], 0, 0, 0);
      }
    }

    // ---- finish staging next chunk (V transpose write + pos) ----
    if (vn){
      #pragma unroll
      for (int cdd = 0; cdd < 4; ++cdd){
        ushort4 wv;
        wv.x = ((const unsigned short*)&rr[0])[cdd];
        wv.y = ((const unsigned short*)&rr[1])[cdd];
        wv.z = ((const unsigned short*)&rr[2])[cdd];
        wv.w = ((const unsigned short*)&rr[3])[cdd];
        *(ushort4*)&V_t[cur ^ 1][(dd0 + cdd) * 72 + key0] = wv;
      }
      if (tid < 64) pos_s[cur ^ 1][tid] = myp;
    }
    __syncthreads();
    if (!vn) break;
  }

  const float invl = 1.0f / l_r;
  float invq[4];
  #pragma unroll
  for (int r = 0; r < 4; ++r) invq[r] = __shfl(invl, (g << 2) | r);
  #pragma unroll
  for (int n = 0; n < 4; ++n){
    #pragma unroll
    for (int r = 0; r < 4; ++r){
      const size_t addr = (size_t)(b * 1024 + qw + 4 * g + r) * HDIM + h * 64 + n * 16 + (lane & 15);
      o[addr] = f2bf(oacc[n][r] * invq[r]);
    }
  }
}

extern "C" void kernel_launch(void* const* d_in, const int* in_sizes, int n_in,
                              void* d_out, int out_size, void* d_ws, size_t ws_size,
                              hipStream_t stream)
{
  (void)in_sizes; (void)n_in; (void)out_size;
  const float* hidden = (const float*)d_in[0];
  const float* ek     = (const float*)d_in[3];
  const float* Wq  = (const float*)d_in[4];
  const float* Wk  = (const float*)d_in[5];
  const float* Wv  = (const float*)d_in[6];
  const float* Wo  = (const float*)d_in[7];
  const float* Wg  = (const float*)d_in[8];
  const float* Wu  = (const float*)d_in[9];
  const float* Wd  = (const float*)d_in[10];
  const float* ln1 = (const float*)d_in[11];
  const float* ln2 = (const float*)d_in[12];
  float* out = (float*)d_out;

  // workspace layout
  unsigned short* Wb = (unsigned short*)d_ws;            // 32M shorts = 64MB
  float* wX = (float*)(Wb + 33554432);                   // 16MB  (x compact; down partials z=2,3)
  float* wR = wX + 4194304;                              // 16MB  (x2 compact)
  unsigned short* bA   = (unsigned short*)(wR + 4194304);// hn/h2 compact, 8MB
  unsigned short* bQKV = bA + 4194304;                   // 4096x3072 compact, 24MB
  unsigned short* bE   = bQKV + 12582912;                // o compact, 8MB
  unsigned short* bG   = bQKV;                           // gu product 32MB (aliases)
  float* act0 = (float*)(bE + 4194304);
  float* act1 = act0 + BSZ;
  float* g0   = act1 + BSZ;
  float* g1   = g0 + BSZ;
  int* idx0 = (int*)(g1 + BSZ);
  int* idx1 = idx0 + BSZ;
  int* cnt0 = idx1 + BSZ;
  int* cnt1 = cnt0 + 4;
  float* wD = (float*)(cnt1 + 4);                        // down partials z=0,1 (bf16), 16MB
  const size_t needed_base  = (size_t)((char*)(cnt1 + 4) - (char*)d_ws);
  const size_t needed_split = (size_t)((char*)(wD + (size_t)BSZ * HDIM) - (char*)d_ws);
  if (ws_size < needed_base) return;
  const bool splitk = (ws_size >= needed_split);

  wtr_all<<<8192, 256, 0, stream>>>(Wq, Wk, Wv, Wo, Wg, Wu, Wd, Wb);
  router_kernel<<<BSZ / 4, 256, 0, stream>>>(hidden, ek, out, act0, act1, g0, g1);
  scan_kernel<<<8, 1024, 0, stream>>>(act0, act1, idx0, idx1, cnt0, cnt1);

  for (int d = 0; d < 2; ++d){
    const float* gate = d ? g1 : g0;
    const int* idx = d ? idx1 : idx0;
    const int* cnt = d ? cnt1 : cnt0;
    const float* ekrow = ek + (size_t)(1 << d) * HDIM;
    unsigned short* wt = Wb + (size_t)d * 16777216;
    const unsigned short* wtqkv = wt;                 // [3072][1024] (Q|K|V)
    const unsigned short* wto = wt + 3145728;
    const unsigned short* wtg = wt + 4194304;
    const unsigned short* wtu = wt + 8388608;
    const unsigned short* wtd = wt + 12582912;

    rms_gather<<<BSZ, 256, 0, stream>>>(out, ekrow, ln1 + (size_t)d * HDIM, idx, cnt, wX, bA);
    // fused QKV + RoPE, 64x64 tiles: grid (48 n, 64 m), bands 32x12
    gemm64_bf16<0,1,4><<<dim3(QKVN / 64, BSZ / 64), 256, 0, stream>>>(
        bA, wtqkv, QKVN, 1024, 1024, bQKV, nullptr, nullptr, nullptr, nullptr, idx, cnt, 32, 12);
    attn_mfma<<<dim3(16, 16, 4), 256, 0, stream>>>(bQKV, bQKV + 1024, bQKV + 2048, idx, cnt, bE, QKVN);
    // o-proj: wR = wX + bE@Wo^T, 64x64 tiles: grid (16 n, 64 m), bands 32x4
    gemm64_bf16<1,0,4><<<dim3(HDIM / 64, BSZ / 64), 256, 0, stream>>>(
        bE, wto, 1024, 1024, 1024, nullptr, wR, wX, nullptr, nullptr, idx, cnt, 32, 4);
    rms_compact<<<BSZ, 256, 0, stream>>>(wR, ln2 + (size_t)d * HDIM, cnt, bA);
    // fused gate-up, 64x64 tiles: grid (64 n, 64 m), bands 32x16
    gemm_gu64_bf16<4><<<dim3(IDIM / 64, BSZ / 64), 256, 0, stream>>>(
        bA, wtg, wtu, IDIM, 1024, bG, cnt, 32, 16);
    if (splitk){
      // down: split-K=4, 64x64 tiles, bf16 partials into wD (z=0,1) and wX (z=2,3)
      gemm64_bf16<2,0,4><<<dim3(HDIM / 64, BSZ / 64, 4), 256, 0, stream>>>(
          bG, wtd, 1024, 4096, 1024, nullptr, nullptr, nullptr,
          (unsigned short*)wD, (unsigned short*)wX, idx, cnt, 32, 4);
      scatter_down4<<<BSZ, 256, 0, stream>>>(
          (const unsigned short*)wD, (const unsigned short*)wX, wR, gate, idx, cnt, out);
    } else {
      // fallback: 64x128 direct EPI1-style accumulate via scatter path not available;
      // use split into wD only if present — otherwise simple per-row loop kernel:
      gemm64_bf16<2,0,4><<<dim3(HDIM / 64, BSZ / 64, 4), 256, 0, stream>>>(
          bG, wtd, 1024, 4096, 1024, nullptr, nullptr, nullptr,
          (unsigned short*)wD, (unsigned short*)wX, idx, cnt, 32, 4);
      scatter_down4<<<BSZ, 256, 0, stream>>>(
          (const unsigned short*)wD, (const unsigned short*)wX, wR, gate, idx, cnt, out);
    }
  }
}

// Round 16
// 479.989 us; speedup vs baseline: 1.0693x; 1.0693x over previous
//
#include <hip/hip_runtime.h>
#include <math.h>

#define BSZ 4096        // B*S
#define HDIM 1024
#define IDIM 4096
#define QKVN 3072
#define NEGF (-1000000000.0f)

typedef __attribute__((ext_vector_type(8))) short bf16x8s;   // 8 bf16 in 4 VGPR
typedef __attribute__((ext_vector_type(4))) float f32x4;
typedef __attribute__((ext_vector_type(2))) unsigned int u32x2;
typedef __attribute__((ext_vector_type(4))) unsigned int u32x4;

#define GLDS(src, dst) __builtin_amdgcn_global_load_lds( \
    (const __attribute__((address_space(1))) void*)(src), \
    (__attribute__((address_space(3))) void*)(dst), 16, 0, 0)

__device__ inline unsigned short f2bf(float f){
  __bf16 h = (__bf16)f;
  return __builtin_bit_cast(unsigned short, h);
}
__device__ inline float bf2f(unsigned short u){
  unsigned x = ((unsigned)u) << 16;
  return __builtin_bit_cast(float, x);
}

__device__ inline float wredSum(float v){
  #pragma unroll
  for (int off = 32; off; off >>= 1) v += __shfl_xor(v, off);
  return v;
}

// ---------------- router: scores, argmax, gates, copy hidden -> out --------------
__global__ __launch_bounds__(256) void router_kernel(
    const float* __restrict__ hidden, const float* __restrict__ ek,
    float* __restrict__ out, float* __restrict__ act0, float* __restrict__ act1,
    float* __restrict__ g0, float* __restrict__ g1)
{
  const int lane = threadIdx.x & 63, wid = threadIdx.x >> 6;
  const int row = blockIdx.x * 4 + wid;
  const float* hr = hidden + (size_t)row * HDIM;
  float4 xv[4];
  float s0 = 0.f, s1 = 0.f, s2 = 0.f, s3 = 0.f;
  #pragma unroll
  for (int tt = 0; tt < 4; ++tt){
    const int o = tt * 256 + lane * 4;
    xv[tt] = *(const float4*)&hr[o];
    const float4 e0 = *(const float4*)&ek[0 * HDIM + o];
    const float4 e1 = *(const float4*)&ek[1 * HDIM + o];
    const float4 e2 = *(const float4*)&ek[2 * HDIM + o];
    const float4 e3 = *(const float4*)&ek[3 * HDIM + o];
    s0 += xv[tt].x * e0.x + xv[tt].y * e0.y + xv[tt].z * e0.z + xv[tt].w * e0.w;
    s1 += xv[tt].x * e1.x + xv[tt].y * e1.y + xv[tt].z * e1.z + xv[tt].w * e1.w;
    s2 += xv[tt].x * e2.x + xv[tt].y * e2.y + xv[tt].z * e2.z + xv[tt].w * e2.w;
    s3 += xv[tt].x * e3.x + xv[tt].y * e3.y + xv[tt].z * e3.z + xv[tt].w * e3.w;
  }
  s0 = wredSum(s0); s1 = wredSum(s1); s2 = wredSum(s2); s3 = wredSum(s3);
  int ch = 0; float mx = s0;
  if (s1 > mx){ mx = s1; ch = 1; }
  if (s2 > mx){ mx = s2; ch = 2; }
  if (s3 > mx){ mx = s3; ch = 3; }
  const float den = expf(s0 - mx) + expf(s1 - mx) + expf(s2 - mx) + expf(s3 - mx);
  const float wsel = 1.0f / den;
  if (lane == 0){
    const float a0 = (float)(ch & 1), a1 = (float)((ch >> 1) & 1);
    act0[row] = a0; act1[row] = a1; g0[row] = a0 * wsel; g1[row] = a1 * wsel;
  }
  float* orow = out + (size_t)row * HDIM;
  #pragma unroll
  for (int tt = 0; tt < 4; ++tt) *(float4*)&orow[tt * 256 + lane * 4] = xv[tt];
}

// ---------------- per-(batch,depth) stable compaction scan ------------------------
__global__ __launch_bounds__(1024) void scan_kernel(
    const float* __restrict__ act0, const float* __restrict__ act1,
    int* __restrict__ idx0, int* __restrict__ idx1,
    int* __restrict__ cnt0, int* __restrict__ cnt1)
{
  __shared__ int s[1024];
  const int b = blockIdx.x >> 1, d = blockIdx.x & 1;
  const float* act = d ? act1 : act0;
  int* idx = d ? idx1 : idx0;
  int* cnt = d ? cnt1 : cnt0;
  const int t = threadIdx.x;
  const int f = (act[b * 1024 + t] > 0.5f) ? 1 : 0;
  s[t] = f;
  __syncthreads();
  for (int off = 1; off < 1024; off <<= 1){
    const int v = (t >= off) ? s[t - off] : 0;
    __syncthreads();
    s[t] += v;
    __syncthreads();
  }
  if (f) idx[b * 1024 + (s[t] - 1)] = b * 1024 + t;
  if (t == 1023) cnt[b] = s[t];
}

// ---------------- ALL weight transposes in ONE dispatch --------------------------
__global__ __launch_bounds__(256) void wtr_all(
    const float* __restrict__ Wq, const float* __restrict__ Wk,
    const float* __restrict__ Wv, const float* __restrict__ Wo,
    const float* __restrict__ Wg, const float* __restrict__ Wu,
    const float* __restrict__ Wd, unsigned short* __restrict__ Wb)
{
  __shared__ float T[64][65];
  const int bidx = blockIdx.x;
  const int d = bidx >> 12;
  const int r = bidx & 4095;
  const float* src; unsigned short* dst; int K, N, tn, tk;
  unsigned short* wt = Wb + (size_t)d * 16777216;
  if (r < 1024){
    const int seg = r >> 8, t = r & 255;
    K = 1024; N = 1024; tn = t & 15; tk = t >> 4;
    const float* s4 = (seg == 0) ? Wq : (seg == 1) ? Wk : (seg == 2) ? Wv : Wo;
    src = s4 + (size_t)d * 1048576;
    dst = wt + (size_t)seg * 1048576;
  } else {
    const int r2 = r - 1024;
    const int seg = r2 >> 10, t = r2 & 1023;
    if (seg == 0){ src = Wg + (size_t)d * 4194304; dst = wt + 4194304;  K = 1024; N = 4096; tn = t & 63; tk = t >> 6; }
    else if (seg == 1){ src = Wu + (size_t)d * 4194304; dst = wt + 8388608;  K = 1024; N = 4096; tn = t & 63; tk = t >> 6; }
    else { src = Wd + (size_t)d * 4194304; dst = wt + 12582912; K = 4096; N = 1024; tn = t & 15; tk = t >> 4; }
  }
  const int k0 = tk * 64, n0 = tn * 64;
  const int tid = threadIdx.x;
  const int tx = tid & 15, ty = tid >> 4;
  #pragma unroll
  for (int i = 0; i < 4; ++i){
    const float4 v = *(const float4*)&src[(size_t)(k0 + ty + i*16) * N + n0 + tx*4];
    T[ty + i*16][tx*4 + 0] = v.x;
    T[ty + i*16][tx*4 + 1] = v.y;
    T[ty + i*16][tx*4 + 2] = v.z;
    T[ty + i*16][tx*4 + 3] = v.w;
  }
  __syncthreads();
  #pragma unroll
  for (int i = 0; i < 4; ++i){
    ushort4 u;
    u.x = f2bf(T[tx*4 + 0][ty + i*16]);
    u.y = f2bf(T[tx*4 + 1][ty + i*16]);
    u.z = f2bf(T[tx*4 + 2][ty + i*16]);
    u.w = f2bf(T[tx*4 + 3][ty + i*16]);
    *(ushort4*)&dst[(size_t)(n0 + ty + i*16) * K + k0 + tx*4] = u;
  }
}

// ---------------- gather rmsnorm: compact row <- full row via idx ----------------
__global__ __launch_bounds__(256) void rms_gather(
    const float* __restrict__ src, const float* __restrict__ ekrow,
    const float* __restrict__ g,
    const int* __restrict__ idx, const int* __restrict__ cnt,
    float* __restrict__ xout, unsigned short* __restrict__ hn)
{
  const int crow = blockIdx.x;
  if ((crow & 1023) >= cnt[crow >> 10]) return;
  const int orig = idx[crow];
  const int t = threadIdx.x;
  const int lane = t & 63, wid = t >> 6;
  const float* sr = src + (size_t)orig * HDIM;
  float4 xv = *(const float4*)&sr[t * 4];
  const float4 e = *(const float4*)&ekrow[t * 4];
  xv.x += e.x; xv.y += e.y; xv.z += e.z; xv.w += e.w;
  float ss = xv.x*xv.x + xv.y*xv.y + xv.z*xv.z + xv.w*xv.w;
  ss = wredSum(ss);
  __shared__ float red[4];
  if (lane == 0) red[wid] = ss;
  __syncthreads();
  const float tot = red[0] + red[1] + red[2] + red[3];
  const float inv = rsqrtf(tot * (1.0f / HDIM) + 1e-6f);
  *(float4*)&xout[(size_t)crow * HDIM + t * 4] = xv;
  const float4 gg = *(const float4*)&g[t * 4];
  ushort4 hu;
  hu.x = f2bf(xv.x * inv * gg.x); hu.y = f2bf(xv.y * inv * gg.y);
  hu.z = f2bf(xv.z * inv * gg.z); hu.w = f2bf(xv.w * inv * gg.w);
  *(ushort4*)&hn[(size_t)crow * HDIM + t * 4] = hu;
}

// ---------------- compact rmsnorm (post-attn) ------------------------------------
__global__ __launch_bounds__(256) void rms_compact(
    const float* __restrict__ src, const float* __restrict__ g,
    const int* __restrict__ cnt, unsigned short* __restrict__ hn)
{
  const int crow = blockIdx.x;
  if ((crow & 1023) >= cnt[crow >> 10]) return;
  const int t = threadIdx.x;
  const int lane = t & 63, wid = t >> 6;
  const float* sr = src + (size_t)crow * HDIM;
  float4 xv = *(const float4*)&sr[t * 4];
  float ss = xv.x*xv.x + xv.y*xv.y + xv.z*xv.z + xv.w*xv.w;
  ss = wredSum(ss);
  __shared__ float red[4];
  if (lane == 0) red[wid] = ss;
  __syncthreads();
  const float tot = red[0] + red[1] + red[2] + red[3];
  const float inv = rsqrtf(tot * (1.0f / HDIM) + 1e-6f);
  const float4 gg = *(const float4*)&g[t * 4];
  ushort4 hu;
  hu.x = f2bf(xv.x * inv * gg.x); hu.y = f2bf(xv.y * inv * gg.y);
  hu.z = f2bf(xv.z * inv * gg.z); hu.w = f2bf(xv.w * inv * gg.w);
  *(ushort4*)&hn[(size_t)crow * HDIM + t * 4] = hu;
}

// ---------------- scatter: out[idx] += gate*(wR + p0+p1+p2+p3) (bf16 partials) ---
__global__ __launch_bounds__(256) void scatter_down4(
    const unsigned short* __restrict__ pA, const unsigned short* __restrict__ pB,
    const float* __restrict__ wR, const float* __restrict__ gate,
    const int* __restrict__ idx, const int* __restrict__ cnt,
    float* __restrict__ out)
{
  const int crow = blockIdx.x;
  if ((crow & 1023) >= cnt[crow >> 10]) return;
  const int orig = idx[crow];
  const int t = threadIdx.x;
  const float gv = gate[orig];
  const size_t off = (size_t)crow * HDIM + t * 4;
  const ushort4 a0 = *(const ushort4*)&pA[off];
  const ushort4 a1 = *(const ushort4*)&pA[4194304 + off];
  const ushort4 a2 = *(const ushort4*)&pB[off];
  const ushort4 a3 = *(const ushort4*)&pB[4194304 + off];
  const float4 rv = *(const float4*)&wR[off];
  float4 ov = *(float4*)&out[(size_t)orig * HDIM + t * 4];
  ov.x += gv * (rv.x + bf2f(a0.x) + bf2f(a1.x) + bf2f(a2.x) + bf2f(a3.x));
  ov.y += gv * (rv.y + bf2f(a0.y) + bf2f(a1.y) + bf2f(a2.y) + bf2f(a3.y));
  ov.z += gv * (rv.z + bf2f(a0.z) + bf2f(a1.z) + bf2f(a2.z) + bf2f(a3.z));
  ov.w += gv * (rv.w + bf2f(a0.w) + bf2f(a1.w) + bf2f(a2.w) + bf2f(a3.w));
  *(float4*)&out[(size_t)orig * HDIM + t * 4] = ov;
}

// swizzle helpers: LDS[row][slot16B] holds global slot (slot ^ fsw(row))
__device__ inline int fsw(int row){ return (row >> 1) & 3; }

// XCD remap for 64(M)x128(N) tiles, m-fast
__device__ inline void xcd_remap64(int bandM, int bandN, int& bm, int& bn){
  const int gx = gridDim.x;
  int bid = blockIdx.y * gx + blockIdx.x;
  const int xcd = bid & 7, c = bid >> 3;
  const int xcdCols = gx / bandN;
  const int xr = xcd / xcdCols, xc = xcd % xcdCols;
  const int dm = c % bandM, dn = c / bandM;
  bm = (xr * bandM + dm) * 64;
  bn = (xc * bandN + dn) * 128;
}

// ---------------- bf16 MFMA GEMM, 64x128 tile (double-buffered core) -------------
// Wave w owns rows [w*16, w*16+16) x all 128 cols: 1 A-frag, 8 B-frags.
// EPI 0: Cb = bf16(acc)  (+ optional fused RoPE on cols < 2048)
// EPI 1: Cf = res + acc                      (f32, compact)
// EPI 2: bf16 partial store by z-slice: pz[cidx] = bf16(acc)
template<int EPI, int ROPE>
__global__ __launch_bounds__(256) void gemm64_bf16(
    const unsigned short* __restrict__ A, const unsigned short* __restrict__ Bt,
    int N, int K, int kspan,
    unsigned short* __restrict__ Cb, float* __restrict__ Cf,
    const float* __restrict__ res,
    unsigned short* __restrict__ pA, unsigned short* __restrict__ pB,
    const int* __restrict__ idx, const int* __restrict__ cnt,
    int bandM, int bandN)
{
  __shared__ __align__(16) unsigned short As[4096];    // 2 bufs x 64x32
  __shared__ __align__(16) unsigned short Bs[8192];    // 2 bufs x 128x32
  const int tid = threadIdx.x;
  const int lane = tid & 63, w = tid >> 6;
  const int g = lane >> 4;
  int bm, bn;
  xcd_remap64(bandM, bandN, bm, bn);
  if ((bm & 1023) >= cnt[bm >> 10]) return;
  const int kb = blockIdx.z * kspan;

  const int rr = tid >> 2, c0 = tid & 3;
  const int scc = (c0 ^ fsw(rr)) * 8;                  // fsw(rr+64) == fsw(rr)
  const unsigned short* gA  = A  + (size_t)(bm + rr) * K + kb + scc;
  const unsigned short* gB0 = Bt + (size_t)(bn + rr) * K + kb + scc;
  const unsigned short* gB1 = Bt + (size_t)(bn + 64 + rr) * K + kb + scc;
  char* ldsA = (char*)As + w * 1024;
  char* ldsB = (char*)Bs + w * 1024;

  const int arow = w * 16 + (lane & 15);
  const int aoffw = arow * 64 + ((g ^ fsw(arow)) * 16);
  int boff[8];
  #pragma unroll
  for (int j = 0; j < 8; ++j){
    const int br = j * 16 + (lane & 15);
    boff[j] = br * 64 + ((g ^ fsw(br)) * 16);
  }

  f32x4 acc[8];
  #pragma unroll
  for (int j = 0; j < 8; ++j){ f32x4 z = {0.f,0.f,0.f,0.f}; acc[j] = z; }

  GLDS(gA, ldsA);
  GLDS(gB0, ldsB); GLDS(gB1, ldsB + 4096);
  gA += 32; gB0 += 32; gB1 += 32;
  __syncthreads();

  const int nk = kspan >> 5;
  for (int kt = 0; kt < nk; ++kt){
    const int cur = kt & 1;
    if (kt + 1 < nk){
      char* dA = ldsA + ((cur ^ 1) ? 4096 : 0);
      char* dB = ldsB + ((cur ^ 1) ? 8192 : 0);
      GLDS(gA, dA); GLDS(gB0, dB); GLDS(gB1, dB + 4096);
      gA += 32; gB0 += 32; gB1 += 32;
    }
    const char* ta = (const char*)As + cur * 4096;
    const char* tb = (const char*)Bs + cur * 8192;
    const bf16x8s af = *(const bf16x8s*)(ta + aoffw);
    #pragma unroll
    for (int j = 0; j < 8; ++j){
      const bf16x8s bf = *(const bf16x8s*)(tb + boff[j]);
      acc[j] = __builtin_amdgcn_mfma_f32_16x16x32_bf16(af, bf, acc[j], 0, 0, 0);
    }
    __syncthreads();
  }

  const int rowb = bm + w * 16 + g * 4;

  if constexpr (ROPE){
    if (bn < 2048){
      float pos[4];
      #pragma unroll
      for (int r = 0; r < 4; ++r) pos[r] = (float)(idx[rowb + r] & 1023);
      // 8 unique angles: (jp, r); reused across both heads (hj)
      float snv[2][4], csv[2][4];
      #pragma unroll
      for (int jp = 0; jp < 2; ++jp){
        const int d0 = (lane & 15) + jp * 16;            // in [0,32)
        const float invf = exp2f((float)d0 * (-13.287712379549449f / 32.0f));
        #pragma unroll
        for (int r = 0; r < 4; ++r)
          __sincosf(pos[r] * invf, &snv[jp][r], &csv[jp][r]);
      }
      #pragma unroll
      for (int hj = 0; hj < 2; ++hj){
        #pragma unroll
        for (int jp = 0; jp < 2; ++jp){
          #pragma unroll
          for (int r = 0; r < 4; ++r){
            const float sn = snv[jp][r], cs = csv[jp][r];
            const float a = acc[hj*4 + jp][r], b = acc[hj*4 + jp + 2][r];
            acc[hj*4 + jp][r]     = a * cs - b * sn;
            acc[hj*4 + jp + 2][r] = b * cs + a * sn;
          }
        }
      }
    }
  }

  unsigned short* po = nullptr;
  if constexpr (EPI == 2){
    const int z = blockIdx.z;
    po = (z < 2) ? (pA + (size_t)z * 4194304) : (pB + (size_t)(z - 2) * 4194304);
  }

  #pragma unroll
  for (int j = 0; j < 8; ++j){
    const int gc = bn + j * 16 + (lane & 15);
    #pragma unroll
    for (int r = 0; r < 4; ++r){
      const size_t cidx = (size_t)(rowb + r) * N + gc;
      if constexpr (EPI == 0){
        Cb[cidx] = f2bf(acc[j][r]);
      } else if constexpr (EPI == 1){
        Cf[cidx] = res[cidx] + acc[j][r];
      } else {
        po[cidx] = f2bf(acc[j][r]);
      }
    }
  }
}

// ---------------- fused gate-up GEMM, 64x128 tile (double-buffered) --------------
__global__ __launch_bounds__(256) void gemm_gu64_bf16(
    const unsigned short* __restrict__ A, const unsigned short* __restrict__ Gt,
    const unsigned short* __restrict__ Ut, int N, int K,
    unsigned short* __restrict__ P, const int* __restrict__ cnt,
    int bandM, int bandN)
{
  __shared__ __align__(16) unsigned short As[4096];
  __shared__ __align__(16) unsigned short Gs[8192];
  __shared__ __align__(16) unsigned short Us[8192];
  const int tid = threadIdx.x;
  const int lane = tid & 63, w = tid >> 6;
  const int g = lane >> 4;
  int bm, bn;
  xcd_remap64(bandM, bandN, bm, bn);
  if ((bm & 1023) >= cnt[bm >> 10]) return;

  const int rr = tid >> 2, c0 = tid & 3;
  const int scc = (c0 ^ fsw(rr)) * 8;
  const unsigned short* gA  = A  + (size_t)(bm + rr) * K + scc;
  const unsigned short* gG0 = Gt + (size_t)(bn + rr) * K + scc;
  const unsigned short* gG1 = Gt + (size_t)(bn + 64 + rr) * K + scc;
  const unsigned short* gU0 = Ut + (size_t)(bn + rr) * K + scc;
  const unsigned short* gU1 = Ut + (size_t)(bn + 64 + rr) * K + scc;
  char* ldsA = (char*)As + w * 1024;
  char* ldsG = (char*)Gs + w * 1024;
  char* ldsU = (char*)Us + w * 1024;

  const int arow = w * 16 + (lane & 15);
  const int aoffw = arow * 64 + ((g ^ fsw(arow)) * 16);
  int boff[8];
  #pragma unroll
  for (int j = 0; j < 8; ++j){
    const int br = j * 16 + (lane & 15);
    boff[j] = br * 64 + ((g ^ fsw(br)) * 16);
  }

  f32x4 accG[8], accU[8];
  #pragma unroll
  for (int j = 0; j < 8; ++j){
    f32x4 z = {0.f,0.f,0.f,0.f}; accG[j] = z; accU[j] = z;
  }

  GLDS(gA, ldsA);
  GLDS(gG0, ldsG); GLDS(gG1, ldsG + 4096);
  GLDS(gU0, ldsU); GLDS(gU1, ldsU + 4096);
  gA += 32; gG0 += 32; gG1 += 32; gU0 += 32; gU1 += 32;
  __syncthreads();

  const int nk = K >> 5;
  for (int kt = 0; kt < nk; ++kt){
    const int cur = kt & 1;
    if (kt + 1 < nk){
      char* dA = ldsA + ((cur ^ 1) ? 4096 : 0);
      char* dG = ldsG + ((cur ^ 1) ? 8192 : 0);
      char* dU = ldsU + ((cur ^ 1) ? 8192 : 0);
      GLDS(gA, dA);
      GLDS(gG0, dG); GLDS(gG1, dG + 4096);
      GLDS(gU0, dU); GLDS(gU1, dU + 4096);
      gA += 32; gG0 += 32; gG1 += 32; gU0 += 32; gU1 += 32;
    }
    const char* ta = (const char*)As + cur * 4096;
    const char* tg = (const char*)Gs + cur * 8192;
    const char* tu = (const char*)Us + cur * 8192;
    const bf16x8s af = *(const bf16x8s*)(ta + aoffw);
    #pragma unroll
    for (int j = 0; j < 8; ++j){
      const bf16x8s gf = *(const bf16x8s*)(tg + boff[j]);
      const bf16x8s uf = *(const bf16x8s*)(tu + boff[j]);
      accG[j] = __builtin_amdgcn_mfma_f32_16x16x32_bf16(af, gf, accG[j], 0, 0, 0);
      accU[j] = __builtin_amdgcn_mfma_f32_16x16x32_bf16(af, uf, accU[j], 0, 0, 0);
    }
    __syncthreads();
  }

  const int rowb = bm + w * 16 + g * 4;
  #pragma unroll
  for (int j = 0; j < 8; ++j){
    const int gc = bn + j * 16 + (lane & 15);
    #pragma unroll
    for (int r = 0; r < 4; ++r){
      const float gv = accG[j][r];
      const float s = gv / (1.0f + expf(-gv));
      P[(size_t)(rowb + r) * N + gc] = f2bf(s * accU[j][r]);
    }
  }
}

// ---------------- MFMA flash attention, double-buffered K/V staging --------------
__global__ __launch_bounds__(256) void attn_mfma(
    const unsigned short* __restrict__ q, const unsigned short* __restrict__ k,
    const unsigned short* __restrict__ v,
    const int* __restrict__ idx, const int* __restrict__ cnt,
    unsigned short* __restrict__ o, int LD)
{
  __shared__ __align__(16) unsigned short K_s[2][4096];    // [64 key][64 d] swizzled
  __shared__ __align__(16) unsigned short V_t[2][64 * 72]; // [64 dd][72 key-pad]
  __shared__ int pos_s[2][64];
  const int tid = threadIdx.x;
  const int lane = tid & 63, w = tid >> 6;
  const int g = lane >> 4;
  const int b = blockIdx.z, h = blockIdx.y, qt = blockIdx.x;
  const int cntb = cnt[b];
  if (qt * 64 >= cntb) return;
  const int qw = qt * 64 + w * 16;
  const int qglob = qw + (lane & 15);                      // compact row within batch
  const int qpos = (qglob < cntb) ? (idx[b * 1024 + qglob] & 1023) : (1 << 29);
  const int lastValid = min(qt * 64 + 63, cntb - 1);
  const int maxQpos = idx[b * 1024 + lastValid] & 1023;

  bf16x8s qa[2];
  {
    const size_t qrow = (size_t)(b * 1024 + qglob) * LD + h * 64;
    qa[0] = *(const bf16x8s*)&q[qrow + g * 8];
    qa[1] = *(const bf16x8s*)&q[qrow + 32 + g * 8];
  }

  f32x4 oacc[4];
  #pragma unroll
  for (int n = 0; n < 4; ++n){ f32x4 z = {0.f,0.f,0.f,0.f}; oacc[n] = z; }
  float m_r = -3.0e38f, l_r = 0.f;

  const int key0 = (tid >> 4) * 4;
  const int dd0  = (tid & 15) * 4;

  // ---- prologue: stage chunk 0 into buf 0 ----
  {
    #pragma unroll
    for (int p = 0; p < 2; ++p){
      const int cc = tid + p * 256;
      const int key = cc >> 3, ci = cc & 7;
      const int sci = (ci ^ (key & 7)) * 8;
      const unsigned short* src = k + (size_t)(b * 1024 + key) * LD + h * 64 + sci;
      GLDS(src, (char*)K_s[0] + p * 4096 + w * 1024);
    }
    ushort4 rr[4];
    #pragma unroll
    for (int kk = 0; kk < 4; ++kk)
      rr[kk] = *(const ushort4*)&v[(size_t)(b * 1024 + key0 + kk) * LD + h * 64 + dd0];
    #pragma unroll
    for (int cdd = 0; cdd < 4; ++cdd){
      ushort4 wv;
      wv.x = ((const unsigned short*)&rr[0])[cdd];
      wv.y = ((const unsigned short*)&rr[1])[cdd];
      wv.z = ((const unsigned short*)&rr[2])[cdd];
      wv.w = ((const unsigned short*)&rr[3])[cdd];
      *(ushort4*)&V_t[0][(dd0 + cdd) * 72 + key0] = wv;
    }
    if (tid < 64)
      pos_s[0][tid] = (tid < cntb) ? (idx[b * 1024 + tid] & 1023) : (1 << 29);
  }
  __syncthreads();

  for (int c = 0; ; ++c){
    const int cur = c & 1;
    const int ck0 = c * 64;
    const int ck0n = ck0 + 64;
    const bool vn = (ck0n < cntb) && ((idx[b * 1024 + ck0n] & 1023) <= maxQpos);

    // ---- issue next chunk's loads before computing this one ----
    ushort4 rr[4];
    int myp = 0;
    if (vn){
      #pragma unroll
      for (int p = 0; p < 2; ++p){
        const int cc = tid + p * 256;
        const int key = cc >> 3, ci = cc & 7;
        const int sci = (ci ^ (key & 7)) * 8;
        const unsigned short* src = k + (size_t)(b * 1024 + ck0n + key) * LD + h * 64 + sci;
        GLDS(src, (char*)K_s[cur ^ 1] + p * 4096 + w * 1024);
      }
      #pragma unroll
      for (int kk = 0; kk < 4; ++kk)
        rr[kk] = *(const ushort4*)&v[(size_t)(b * 1024 + ck0n + key0 + kk) * LD + h * 64 + dd0];
      if (tid < 64)
        myp = (ck0n + tid < cntb) ? (idx[b * 1024 + ck0n + tid] & 1023) : (1 << 29);
    }

    // ---- compute chunk c from buf cur ----
    f32x4 s[4];
    #pragma unroll
    for (int mt = 0; mt < 4; ++mt){ f32x4 z = {0.f,0.f,0.f,0.f}; s[mt] = z; }
    #pragma unroll
    for (int kd = 0; kd < 2; ++kd){
      #pragma unroll
      for (int mt = 0; mt < 4; ++mt){
        const int row = mt * 16 + (lane & 15);
        const int slot = (kd * 4 + g) ^ (row & 7);
        const bf16x8s kf = *(const bf16x8s*)((const char*)K_s[cur] + row * 128 + slot * 16);
        s[mt] = __builtin_amdgcn_mfma_f32_16x16x32_bf16(kf, qa[kd], s[mt], 0, 0, 0);
      }
    }

    float sval[4][4];
    float rm = -3.0e38f;
    #pragma unroll
    for (int mt = 0; mt < 4; ++mt){
      const int4 pv = *(const int4*)&pos_s[cur][mt * 16 + g * 4];
      const int kp[4] = {pv.x, pv.y, pv.z, pv.w};
      #pragma unroll
      for (int r = 0; r < 4; ++r){
        float x = (kp[r] > qpos) ? -2.0e9f : s[mt][r] * 0.125f;
        sval[mt][r] = x;
        rm = fmaxf(rm, x);
      }
    }
    rm = fmaxf(rm, __shfl_xor(rm, 16));
    rm = fmaxf(rm, __shfl_xor(rm, 32));
    const float mn = fmaxf(m_r, rm);
    const float sc = expf(m_r - mn);
    float psum = 0.f;
    u32x2 pa[4];
    #pragma unroll
    for (int mt = 0; mt < 4; ++mt){
      float p0 = expf(sval[mt][0] - mn), p1 = expf(sval[mt][1] - mn);
      float p2 = expf(sval[mt][2] - mn), p3 = expf(sval[mt][3] - mn);
      psum += (p0 + p1) + (p2 + p3);
      u32x2 pw;
      pw[0] = (unsigned)f2bf(p0) | ((unsigned)f2bf(p1) << 16);
      pw[1] = (unsigned)f2bf(p2) | ((unsigned)f2bf(p3) << 16);
      pa[mt] = pw;
    }
    psum += __shfl_xor(psum, 16);
    psum += __shfl_xor(psum, 32);
    l_r = l_r * sc + psum;
    m_r = mn;

    float scq[4];
    #pragma unroll
    for (int r = 0; r < 4; ++r) scq[r] = __shfl(sc, (g << 2) | r);
    #pragma unroll
    for (int n = 0; n < 4; ++n)
      #pragma unroll
      for (int r = 0; r < 4; ++r) oacc[n][r] *= scq[r];

    #pragma unroll
    for (int half = 0; half < 2; ++half){
      unsigned aw[4];
      #pragma unroll
      for (int t = 0; t < 4; ++t){
        const int sidx = (lane & 15) + 16 * (2 * (g & 1) + (t >> 1));
        const unsigned wa = __shfl(pa[2 * half][t & 1], sidx);
        const unsigned wb = __shfl(pa[2 * half + 1][t & 1], sidx);
        aw[t] = (g < 2) ? wa : wb;
      }
      u32x4 av4 = {aw[0], aw[1], aw[2], aw[3]};
      const bf16x8s pfrag = __builtin_bit_cast(bf16x8s, av4);
      #pragma unroll
      for (int n = 0; n < 4; ++n){
        const bf16x8s vfrag = *(const bf16x8s*)&V_t[cur][(n * 16 + (lane & 15)) * 72 + half * 32 + g * 8];
        oacc[n] = __builtin_amdgcn_mfma_f32_16x16x32_bf16(pfrag, vfrag, oacc[n], 0, 0, 0);
      }
    }

    // ---- finish staging next chunk (V transpose write + pos) ----
    if (vn){
      #pragma unroll
      for (int cdd = 0; cdd < 4; ++cdd){
        ushort4 wv;
        wv.x = ((const unsigned short*)&rr[0])[cdd];
        wv.y = ((const unsigned short*)&rr[1])[cdd];
        wv.z = ((const unsigned short*)&rr[2])[cdd];
        wv.w = ((const unsigned short*)&rr[3])[cdd];
        *(ushort4*)&V_t[cur ^ 1][(dd0 + cdd) * 72 + key0] = wv;
      }
      if (tid < 64) pos_s[cur ^ 1][tid] = myp;
    }
    __syncthreads();
    if (!vn) break;
  }

  const float invl = 1.0f / l_r;
  float invq[4];
  #pragma unroll
  for (int r = 0; r < 4; ++r) invq[r] = __shfl(invl, (g << 2) | r);
  #pragma unroll
  for (int n = 0; n < 4; ++n){
    #pragma unroll
    for (int r = 0; r < 4; ++r){
      const size_t addr = (size_t)(b * 1024 + qw + 4 * g + r) * HDIM + h * 64 + n * 16 + (lane & 15);
      o[addr] = f2bf(oacc[n][r] * invq[r]);
    }
  }
}

extern "C" void kernel_launch(void* const* d_in, const int* in_sizes, int n_in,
                              void* d_out, int out_size, void* d_ws, size_t ws_size,
                              hipStream_t stream)
{
  (void)in_sizes; (void)n_in; (void)out_size;
  const float* hidden = (const float*)d_in[0];
  const float* ek     = (const float*)d_in[3];
  const float* Wq  = (const float*)d_in[4];
  const float* Wk  = (const float*)d_in[5];
  const float* Wv  = (const float*)d_in[6];
  const float* Wo  = (const float*)d_in[7];
  const float* Wg  = (const float*)d_in[8];
  const float* Wu  = (const float*)d_in[9];
  const float* Wd  = (const float*)d_in[10];
  const float* ln1 = (const float*)d_in[11];
  const float* ln2 = (const float*)d_in[12];
  float* out = (float*)d_out;

  // workspace layout
  unsigned short* Wb = (unsigned short*)d_ws;            // 32M shorts = 64MB
  float* wX = (float*)(Wb + 33554432);                   // 16MB  (x compact; down partials z=2,3)
  float* wR = wX + 4194304;                              // 16MB  (x2 compact)
  unsigned short* bA   = (unsigned short*)(wR + 4194304);// hn/h2 compact, 8MB
  unsigned short* bQKV = bA + 4194304;                   // 4096x3072 compact, 24MB
  unsigned short* bE   = bQKV + 12582912;                // o compact, 8MB
  unsigned short* bG   = bQKV;                           // gu product 32MB (aliases)
  float* act0 = (float*)(bE + 4194304);
  float* act1 = act0 + BSZ;
  float* g0   = act1 + BSZ;
  float* g1   = g0 + BSZ;
  int* idx0 = (int*)(g1 + BSZ);
  int* idx1 = idx0 + BSZ;
  int* cnt0 = idx1 + BSZ;
  int* cnt1 = cnt0 + 4;
  float* wD = (float*)(cnt1 + 4);                        // down partials z=0,1 (bf16), 16MB
  const size_t needed = (size_t)((char*)(wD + (size_t)BSZ * HDIM) - (char*)d_ws);
  if (ws_size < needed) return;

  wtr_all<<<8192, 256, 0, stream>>>(Wq, Wk, Wv, Wo, Wg, Wu, Wd, Wb);
  router_kernel<<<BSZ / 4, 256, 0, stream>>>(hidden, ek, out, act0, act1, g0, g1);
  scan_kernel<<<8, 1024, 0, stream>>>(act0, act1, idx0, idx1, cnt0, cnt1);

  for (int d = 0; d < 2; ++d){
    const float* gate = d ? g1 : g0;
    const int* idx = d ? idx1 : idx0;
    const int* cnt = d ? cnt1 : cnt0;
    const float* ekrow = ek + (size_t)(1 << d) * HDIM;
    unsigned short* wt = Wb + (size_t)d * 16777216;
    const unsigned short* wtqkv = wt;                 // [3072][1024] (Q|K|V)
    const unsigned short* wto = wt + 3145728;
    const unsigned short* wtg = wt + 4194304;
    const unsigned short* wtu = wt + 8388608;
    const unsigned short* wtd = wt + 12582912;

    rms_gather<<<BSZ, 256, 0, stream>>>(out, ekrow, ln1 + (size_t)d * HDIM, idx, cnt, wX, bA);
    // fused QKV + RoPE, 64x128 tiles: grid (24 n, 64 m), bands 32x6
    gemm64_bf16<0,1><<<dim3(QKVN / 128, BSZ / 64), 256, 0, stream>>>(
        bA, wtqkv, QKVN, 1024, 1024, bQKV, nullptr, nullptr, nullptr, nullptr, idx, cnt, 32, 6);
    attn_mfma<<<dim3(16, 16, 4), 256, 0, stream>>>(bQKV, bQKV + 1024, bQKV + 2048, idx, cnt, bE, QKVN);
    // o-proj: wR = wX + bE@Wo^T, 64x128 tiles
    gemm64_bf16<1,0><<<dim3(HDIM / 128, BSZ / 64), 256, 0, stream>>>(
        bE, wto, 1024, 1024, 1024, nullptr, wR, wX, nullptr, nullptr, idx, cnt, 32, 2);
    rms_compact<<<BSZ, 256, 0, stream>>>(wR, ln2 + (size_t)d * HDIM, cnt, bA);
    // fused gate-up, 64x128 tiles: grid (32 n, 64 m), bands 32x8
    gemm_gu64_bf16<<<dim3(IDIM / 128, BSZ / 64), 256, 0, stream>>>(
        bA, wtg, wtu, IDIM, 1024, bG, cnt, 32, 8);
    // down: split-K=4, bf16 partials into wD (z=0,1) and wX (z=2,3; wX dead here)
    gemm64_bf16<2,0><<<dim3(HDIM / 128, BSZ / 64, 4), 256, 0, stream>>>(
        bG, wtd, 1024, 4096, 1024, nullptr, nullptr, nullptr,
        (unsigned short*)wD, (unsigned short*)wX, idx, cnt, 32, 2);
    scatter_down4<<<BSZ, 256, 0, stream>>>(
        (const unsigned short*)wD, (const unsigned short*)wX, wR, gate, idx, cnt, out);
  }
}